// Round 2
// baseline (14633.537 us; speedup 1.0000x reference)
//
#include <hip/hip_runtime.h>
#include <hip/hip_bf16.h>
#include <math.h>

#define D 512
#define H 8
#define FF 2048
#define V 10000
#define NLAYERS 6
#define BB 8
#define S 512
#define DK 64
#define BS (BB*S)   /* 4096 rows */

// Per the harness instructions, dtypes follow the REFERENCE: float32 in/out.
// (Round-1 NaN was consistent with misreading f32 buffers as bf16.)
typedef float WT;   // weight/bias/embedding element type
typedef float OT;   // output element type

__device__ __forceinline__ float tof(float x){ return x; }
__device__ __forceinline__ float tof(__hip_bfloat16 x){ return __bfloat162float(x); }
__device__ __forceinline__ void stor(float* p, float v){ *p = v; }
__device__ __forceinline__ void stor(__hip_bfloat16* p, float v){ *p = __float2bfloat16(v); }

// ---------------------------------------------------------------------------
// Embedding + sinusoidal positional encoding: x[r,d] = emb[tok[r],d] + pe[s,d]
// ---------------------------------------------------------------------------
__global__ __launch_bounds__(256) void embed_kernel(const int* __restrict__ tok,
                                                    const WT* __restrict__ emb,
                                                    float* __restrict__ x)
{
    int r = blockIdx.x;            // [0, BS)
    int s = r % S;
    int tk = tok[r];
    int t = threadIdx.x;
    const float c = -logf(10000.f) / (float)D;
#pragma unroll
    for (int p = 0; p < 2; ++p) {
        int d = t + p * 256;
        int i2 = d & ~1;                       // even index of the sin/cos pair
        float ang = (float)s * expf((float)i2 * c);
        float pe = (d & 1) ? cosf(ang) : sinf(ang);
        x[(long)r * D + d] = tof(emb[(long)tk * D + d]) + pe;
    }
}

// ---------------------------------------------------------------------------
// Masked softmax over rows of scores [B*H, S, S].
// causal=1 : keep j <= i.  causal=0 : keep tok[b*S+j] != 0 (key padding mask).
// ---------------------------------------------------------------------------
__global__ __launch_bounds__(256) void softmax_kernel(float* __restrict__ sc,
                                                      const int* __restrict__ tok,
                                                      int causal)
{
    __shared__ float red[4];
    long r = blockIdx.x;                 // [0, B*H*S)
    int i = (int)(r % S);
    int b = (int)(r / ((long)H * S));
    float* row = sc + r * (long)S;
    int t = threadIdx.x;
    float v0 = row[t], v1 = row[t + 256];
    if (causal) {
        if (t > i)        v0 = -INFINITY;
        if (t + 256 > i)  v1 = -INFINITY;
    } else {
        if (tok[b * S + t] == 0)        v0 = -INFINITY;
        if (tok[b * S + t + 256] == 0)  v1 = -INFINITY;
    }
    float m = fmaxf(v0, v1);
    for (int off = 32; off; off >>= 1) m = fmaxf(m, __shfl_down(m, off));
    if ((t & 63) == 0) red[t >> 6] = m;
    __syncthreads();
    m = fmaxf(fmaxf(red[0], red[1]), fmaxf(red[2], red[3]));
    __syncthreads();
    float e0 = expf(v0 - m), e1 = expf(v1 - m);   // expf(-inf)=0
    float ssum = e0 + e1;
    for (int off = 32; off; off >>= 1) ssum += __shfl_down(ssum, off);
    if ((t & 63) == 0) red[t >> 6] = ssum;
    __syncthreads();
    ssum = red[0] + red[1] + red[2] + red[3];
    float inv = 1.0f / ssum;
    row[t]       = e0 * inv;
    row[t + 256] = e1 * inv;
}

// ---------------------------------------------------------------------------
// In-place residual + LayerNorm: x[r,:] = LN(x[r,:] + a[r,:]) * g + b
// ---------------------------------------------------------------------------
__global__ __launch_bounds__(256) void ln_kernel(float* __restrict__ x,
                                                 const float* __restrict__ a,
                                                 const WT* __restrict__ g,
                                                 const WT* __restrict__ bb)
{
    __shared__ float red[4];
    long r = blockIdx.x;                 // [0, BS)
    float* xr = x + r * D;
    const float* ar = a + r * D;
    int t = threadIdx.x;
    float v0 = xr[t] + ar[t];
    float v1 = xr[t + 256] + ar[t + 256];
    float s = v0 + v1;
    for (int off = 32; off; off >>= 1) s += __shfl_down(s, off);
    if ((t & 63) == 0) red[t >> 6] = s;
    __syncthreads();
    float mu = (red[0] + red[1] + red[2] + red[3]) * (1.0f / D);
    __syncthreads();
    float d0 = v0 - mu, d1 = v1 - mu;
    float q = d0 * d0 + d1 * d1;
    for (int off = 32; off; off >>= 1) q += __shfl_down(q, off);
    if ((t & 63) == 0) red[t >> 6] = q;
    __syncthreads();
    float var = (red[0] + red[1] + red[2] + red[3]) * (1.0f / D);
    float inv = rsqrtf(var + 1e-5f);
    xr[t]       = d0 * inv * tof(g[t])       + tof(bb[t]);
    xr[t + 256] = d1 * inv * tof(g[t + 256]) + tof(bb[t + 256]);
}

// ---------------------------------------------------------------------------
// Generic batched tiled GEMM.
//   C[z][m,n] = alpha * sum_k A[z][m,k] * B'[z][k,n] (+ bias[n]) (opt. ReLU)
//   B' = B (TRANSB=0, B is [K,N] ld=ldb) or B^T (TRANSB=1, B is [N,K] ld=ldb)
//   z decomposes as zb = z/Hdiv, zh = z%Hdiv; per-operand offsets zb*s?b+zh*s?h.
// Tile 64x64, BK=16, 256 threads, 4x4 micro-tile per thread.
// K must be a multiple of 16 (holds: 512, 2048, 64).
// ---------------------------------------------------------------------------
template<typename BT, typename CT, bool TRANSB, bool RELU>
__global__ __launch_bounds__(256) void gemm_kernel(
    const float* __restrict__ A, int lda, long sAb, long sAh,
    const BT* __restrict__ Bm, int ldb, long sBb, long sBh,
    const BT* __restrict__ bias,
    CT* __restrict__ C, int ldc, long sCb, long sCh,
    int M, int N, int K, int Hdiv, float alpha)
{
    __shared__ float As[16][68];   // [k][m], pad keeps 16B align + 2-way banks
    __shared__ float Bs[16][68];   // [k][n]
    int z = blockIdx.z;
    int zb = z / Hdiv, zh = z % Hdiv;
    A  += (long)zb * sAb + (long)zh * sAh;
    Bm += (long)zb * sBb + (long)zh * sBh;
    C  += (long)zb * sCb + (long)zh * sCh;
    int m0 = blockIdx.y * 64;
    int n0 = blockIdx.x * 64;
    int t = threadIdx.x;
    int tx = t & 15, ty = t >> 4;
    float acc[4][4] = {};
    for (int k0 = 0; k0 < K; k0 += 16) {
#pragma unroll
        for (int i = 0; i < 4; ++i) {          // A tile 64(m) x 16(k)
            int e = t + 256 * i;
            int m = e >> 4, kk = e & 15;
            float v = 0.f;
            int gm = m0 + m;
            if (gm < M) v = A[(long)gm * lda + (k0 + kk)];
            As[kk][m] = v;
        }
#pragma unroll
        for (int i = 0; i < 4; ++i) {          // B tile 16(k) x 64(n)
            int e = t + 256 * i;
            float v = 0.f;
            if (TRANSB) {
                int n = e >> 4, kk = e & 15;   // coalesced along k
                int gn = n0 + n;
                if (gn < N) v = tof(Bm[(long)gn * ldb + (k0 + kk)]);
                Bs[kk][n] = v;
            } else {
                int kk = e >> 6, n = e & 63;   // coalesced along n
                int gn = n0 + n;
                if (gn < N) v = tof(Bm[(long)(k0 + kk) * ldb + gn]);
                Bs[kk][n] = v;
            }
        }
        __syncthreads();
#pragma unroll
        for (int kk = 0; kk < 16; ++kk) {
            float4 a4 = *(const float4*)&As[kk][ty * 4];
            float4 b4 = *(const float4*)&Bs[kk][tx * 4];
            float av[4] = {a4.x, a4.y, a4.z, a4.w};
            float bv[4] = {b4.x, b4.y, b4.z, b4.w};
#pragma unroll
            for (int i2 = 0; i2 < 4; ++i2)
#pragma unroll
                for (int j = 0; j < 4; ++j)
                    acc[i2][j] += av[i2] * bv[j];
        }
        __syncthreads();
    }
#pragma unroll
    for (int i2 = 0; i2 < 4; ++i2) {
        int m = m0 + ty * 4 + i2;
        if (m >= M) continue;
#pragma unroll
        for (int j = 0; j < 4; ++j) {
            int n = n0 + tx * 4 + j;
            if (n >= N) continue;
            float v = acc[i2][j] * alpha;
            if (bias) v += tof(bias[n]);
            if (RELU) v = fmaxf(v, 0.f);
            stor(&C[(long)m * ldc + n], v);
        }
    }
}

// ---------------------------------------------------------------------------
extern "C" void kernel_launch(void* const* d_in, const int* in_sizes, int n_in,
                              void* d_out, int out_size, void* d_ws, size_t ws_size,
                              hipStream_t stream)
{
    const int* src      = (const int*)d_in[0];
    const int* tgt      = (const int*)d_in[1];
    const WT*  src_emb  = (const WT*)d_in[2];
    const WT*  tgt_emb  = (const WT*)d_in[3];
    const WT* enc_qkvo_w = (const WT*)d_in[4];
    const WT* enc_qkvo_b = (const WT*)d_in[5];
    const WT* enc_ff1_w  = (const WT*)d_in[6];
    const WT* enc_ff1_b  = (const WT*)d_in[7];
    const WT* enc_ff2_w  = (const WT*)d_in[8];
    const WT* enc_ff2_b  = (const WT*)d_in[9];
    const WT* enc_ln_g   = (const WT*)d_in[10];
    const WT* enc_ln_b   = (const WT*)d_in[11];
    const WT* dec_sa_w   = (const WT*)d_in[12];
    const WT* dec_sa_b   = (const WT*)d_in[13];
    const WT* dec_ca_w   = (const WT*)d_in[14];
    const WT* dec_ca_b   = (const WT*)d_in[15];
    const WT* dec_ff1_w  = (const WT*)d_in[16];
    const WT* dec_ff1_b  = (const WT*)d_in[17];
    const WT* dec_ff2_w  = (const WT*)d_in[18];
    const WT* dec_ff2_b  = (const WT*)d_in[19];
    const WT* dec_ln_g   = (const WT*)d_in[20];
    const WT* dec_ln_b   = (const WT*)d_in[21];
    const WT* out_w      = (const WT*)d_in[22];
    const WT* out_b      = (const WT*)d_in[23];
    OT* out = (OT*)d_out;

    // Workspace layout (f32), 112 MB total via aliasing:
    //   persistent: bx, by, bmha (3 x 8 MB)
    //   attention-transient: bq, bk, bv (3 x 8 MB); batt aliases bq (Q dead
    //     after the scores GEMM)
    //   big region (64 MB): bsc (scores) during attention | bffn (FF hidden,
    //     32 MB) during FFN — never live simultaneously
    float* bx   = (float*)d_ws;
    float* by   = bx   + (size_t)BS * D;
    float* bmha = by   + (size_t)BS * D;
    float* bq   = bmha + (size_t)BS * D;
    float* bk   = bq   + (size_t)BS * D;
    float* bv   = bk   + (size_t)BS * D;
    float* batt = bq;                        // alias
    float* bsc  = bv   + (size_t)BS * D;     // [B*H, S, S]
    float* bffn = bsc;                       // alias, [BS, FF]

    dim3 blk(256);

    auto gemm_w = [&](const float* Ap, const WT* Wp, const WT* Bp, float* Cp,
                      int M, int N, int K, bool relu) {
        dim3 g((N + 63) / 64, (M + 63) / 64, 1);
        if (relu)
            gemm_kernel<WT, float, false, true><<<g, blk, 0, stream>>>(
                Ap, K, 0, 0, Wp, N, 0, 0, Bp, Cp, N, 0, 0, M, N, K, 1, 1.0f);
        else
            gemm_kernel<WT, float, false, false><<<g, blk, 0, stream>>>(
                Ap, K, 0, 0, Wp, N, 0, 0, Bp, Cp, N, 0, 0, M, N, K, 1, 1.0f);
    };

    auto attn = [&](const float* xq, const float* xkv, const WT* w, const WT* b,
                    const int* masktok, int causal, float* outbuf) {
        gemm_w(xq,  w + 0 * (size_t)D * D, b + 0 * D, bq, BS, D, D, false);
        gemm_w(xkv, w + 1 * (size_t)D * D, b + 1 * D, bk, BS, D, D, false);
        gemm_w(xkv, w + 2 * (size_t)D * D, b + 2 * D, bv, BS, D, D, false);
        {   // scores[z] = 0.125 * Q K^T   (z = b*H + h)
            dim3 g(S / 64, S / 64, BB * H);
            gemm_kernel<float, float, true, false><<<g, blk, 0, stream>>>(
                bq, D, (long)S * D, DK, bk, D, (long)S * D, DK, nullptr,
                bsc, S, (long)H * S * S, (long)S * S, S, S, DK, H, 0.125f);
        }
        softmax_kernel<<<dim3(BB * H * S), blk, 0, stream>>>(bsc, masktok, causal);
        {   // context[z] = P V   (batt aliases bq — Q is dead here)
            dim3 g(1, S / 64, BB * H);
            gemm_kernel<float, float, false, false><<<g, blk, 0, stream>>>(
                bsc, S, (long)H * S * S, (long)S * S, bv, D, (long)S * D, DK, nullptr,
                batt, D, (long)S * D, DK, S, DK, S, H, 1.0f);
        }
        gemm_w(batt, w + 3 * (size_t)D * D, b + 3 * D, outbuf, BS, D, D, false);
    };

    // ---------------- encoder ----------------
    embed_kernel<<<dim3(BS), blk, 0, stream>>>(src, src_emb, bx);
    for (int l = 0; l < NLAYERS; ++l) {
        const WT* w = enc_qkvo_w + (size_t)l * 4 * D * D;
        const WT* b = enc_qkvo_b + (size_t)l * 4 * D;
        attn(bx, bx, w, b, src, 0, bmha);
        ln_kernel<<<dim3(BS), blk, 0, stream>>>(bx, bmha,
            enc_ln_g + (size_t)l * 2 * D, enc_ln_b + (size_t)l * 2 * D);
        gemm_w(bx, enc_ff1_w + (size_t)l * D * FF, enc_ff1_b + (size_t)l * FF,
               bffn, BS, FF, D, true);
        gemm_w(bffn, enc_ff2_w + (size_t)l * FF * D, enc_ff2_b + (size_t)l * D,
               bmha, BS, D, FF, false);
        ln_kernel<<<dim3(BS), blk, 0, stream>>>(bx, bmha,
            enc_ln_g + (size_t)l * 2 * D + D, enc_ln_b + (size_t)l * 2 * D + D);
    }

    // ---------------- decoder ----------------
    embed_kernel<<<dim3(BS), blk, 0, stream>>>(tgt, tgt_emb, by);
    for (int l = 0; l < NLAYERS; ++l) {
        // masked self-attention (causal only, per reference)
        attn(by, by, dec_sa_w + (size_t)l * 4 * D * D, dec_sa_b + (size_t)l * 4 * D,
             nullptr, 1, bmha);
        ln_kernel<<<dim3(BS), blk, 0, stream>>>(by, bmha,
            dec_ln_g + (size_t)l * 3 * D, dec_ln_b + (size_t)l * 3 * D);
        // cross-attention; NOTE: reference masks keys with TGT padding (bug-for-bug)
        attn(by, bx, dec_ca_w + (size_t)l * 4 * D * D, dec_ca_b + (size_t)l * 4 * D,
             tgt, 0, bmha);
        ln_kernel<<<dim3(BS), blk, 0, stream>>>(by, bmha,
            dec_ln_g + (size_t)l * 3 * D + D, dec_ln_b + (size_t)l * 3 * D + D);
        gemm_w(by, dec_ff1_w + (size_t)l * D * FF, dec_ff1_b + (size_t)l * FF,
               bffn, BS, FF, D, true);
        gemm_w(bffn, dec_ff2_w + (size_t)l * FF * D, dec_ff2_b + (size_t)l * D,
               bmha, BS, D, FF, false);
        ln_kernel<<<dim3(BS), blk, 0, stream>>>(by, bmha,
            dec_ln_g + (size_t)l * 3 * D + 2 * D, dec_ln_b + (size_t)l * 3 * D + 2 * D);
    }

    // ---------------- final projection to vocab ----------------
    {
        dim3 g((V + 63) / 64, BS / 64, 1);
        gemm_kernel<WT, OT, false, false><<<g, blk, 0, stream>>>(
            by, D, 0, 0, out_w, V, 0, 0, out_b, out, V, 0, 0, BS, V, D, 1, 1.0f);
    }
}